// Round 1
// baseline (1423.450 us; speedup 1.0000x reference)
//
#include <hip/hip_runtime.h>
#include <hip/hip_bf16.h>
#include <math.h>

// ---------------- constants (from reference) ----------------
#define F_IN   336
#define HC     200      // H*C
#define Cch    100      // channels per head
#define SLOPE  0.2f
#define SCAN_BS 256

// ---------------- CSR build ----------------
__global__ void init_deg(int* deg, int n) {
    int i = blockIdx.x * 256 + threadIdx.x;
    if (i < n) deg[i] = 1;   // self-loop
}

__global__ void count_deg(const int* __restrict__ dst, int* deg, int e) {
    int i = blockIdx.x * 256 + threadIdx.x;
    if (i < e) atomicAdd(&deg[dst[i]], 1);
}

__global__ void scan_block(const int* __restrict__ deg, int* incl, int* bsums, int n) {
    __shared__ int sm[SCAN_BS];
    int i = blockIdx.x * SCAN_BS + threadIdx.x;
    int v = (i < n) ? deg[i] : 0;
    sm[threadIdx.x] = v;
    __syncthreads();
    for (int off = 1; off < SCAN_BS; off <<= 1) {
        int t = (threadIdx.x >= off) ? sm[threadIdx.x - off] : 0;
        __syncthreads();
        sm[threadIdx.x] += t;
        __syncthreads();
    }
    if (i < n) incl[i] = sm[threadIdx.x];
    if (threadIdx.x == SCAN_BS - 1) bsums[blockIdx.x] = sm[threadIdx.x];
}

__global__ void scan_sums(int* bsums, int nb) {
    __shared__ int sm[SCAN_BS];
    int v = (threadIdx.x < nb) ? bsums[threadIdx.x] : 0;
    sm[threadIdx.x] = v;
    __syncthreads();
    for (int off = 1; off < SCAN_BS; off <<= 1) {
        int t = (threadIdx.x >= off) ? sm[threadIdx.x - off] : 0;
        __syncthreads();
        sm[threadIdx.x] += t;
        __syncthreads();
    }
    if (threadIdx.x < nb) bsums[threadIdx.x] = sm[threadIdx.x] - v;  // exclusive
}

__global__ void scan_final(const int* __restrict__ incl, const int* __restrict__ deg,
                           const int* __restrict__ bsums, int* row_ptr, int* cursor, int n) {
    int i = blockIdx.x * SCAN_BS + threadIdx.x;
    if (i < n) {
        int inc = incl[i] + bsums[i / SCAN_BS];
        int ex  = inc - deg[i];
        row_ptr[i] = ex;
        cursor[i]  = ex;
        if (i == n - 1) row_ptr[n] = inc;
    }
}

__global__ void fill_csr(const int* __restrict__ src, const int* __restrict__ dst,
                         int* cursor, int* col_src, int e, int n) {
    int i = blockIdx.x * 256 + threadIdx.x;
    int te = e + n;
    if (i >= te) return;
    int s, d;
    if (i < e) { s = src[i]; d = dst[i]; }
    else       { s = i - e;  d = i - e; }
    int pos = atomicAdd(&cursor[d], 1);
    col_src[pos] = s;
}

// ---------------- fp32 GEMM: C[M,Nc] = A[M,K] @ B[K,Nc] ----------------
#define BM 64
#define BN 64
#define BK 16
__global__ __launch_bounds__(256) void gemm_f32(
    const float* __restrict__ A, const float* __restrict__ B, float* __restrict__ Cc,
    int M, int K, int Nc)
{
    __shared__ float As[BK][BM + 4];
    __shared__ float Bs[BK][BN + 4];
    int tid = threadIdx.x;
    int tx = tid & 15, ty = tid >> 4;
    int r0 = blockIdx.x * BM, c0 = blockIdx.y * BN;
    float acc[4][4] = {};
    int aRow = tid >> 2, aC4 = (tid & 3) * 4;   // A tile 64x16
    int bRow = tid >> 4, bC4 = (tid & 15) * 4;  // B tile 16x64

    for (int kc = 0; kc < K; kc += BK) {
        {
            int gr = r0 + aRow;
#pragma unroll
            for (int j = 0; j < 4; j++) {
                int gc = kc + aC4 + j;
                As[aC4 + j][aRow] = (gr < M && gc < K) ? A[(size_t)gr * K + gc] : 0.f;
            }
        }
        {
            int gr = kc + bRow;
#pragma unroll
            for (int j = 0; j < 4; j++) {
                int gc = c0 + bC4 + j;
                Bs[bRow][bC4 + j] = (gr < K && gc < Nc) ? B[(size_t)gr * Nc + gc] : 0.f;
            }
        }
        __syncthreads();
#pragma unroll
        for (int k = 0; k < BK; k++) {
            float ar[4], br[4];
#pragma unroll
            for (int i = 0; i < 4; i++) ar[i] = As[k][ty * 4 + i];
#pragma unroll
            for (int j = 0; j < 4; j++) br[j] = Bs[k][tx * 4 + j];
#pragma unroll
            for (int i = 0; i < 4; i++)
#pragma unroll
                for (int j = 0; j < 4; j++)
                    acc[i][j] = fmaf(ar[i], br[j], acc[i][j]);
        }
        __syncthreads();
    }
#pragma unroll
    for (int i = 0; i < 4; i++) {
        int gr = r0 + ty * 4 + i;
        if (gr >= M) continue;
#pragma unroll
        for (int j = 0; j < 4; j++) {
            int gc = c0 + tx * 4 + j;
            if (gc < Nc) Cc[(size_t)gr * Nc + gc] = acc[i][j];
        }
    }
}

// ---------------- attention scores es/ed (wave per node) ----------------
__global__ __launch_bounds__(256) void gat_scores(
    const float* __restrict__ h, const float* __restrict__ asrc, const float* __restrict__ adst,
    float* __restrict__ es, float* __restrict__ ed, int n_nodes)
{
    int wave = threadIdx.x >> 6, lane = threadIdx.x & 63;
    int n = blockIdx.x * 4 + wave;
    if (n >= n_nodes) return;
#pragma unroll
    for (int hd = 0; hd < 2; hd++) {
        const float* hr = h + (size_t)n * HC + hd * Cch;
        const float* as = asrc + hd * Cch;
        const float* ad = adst + hd * Cch;
        float v = hr[lane];
        float ps = v * as[lane];
        float pd = v * ad[lane];
        if (lane < Cch - 64) {
            float v2 = hr[lane + 64];
            ps += v2 * as[lane + 64];
            pd += v2 * ad[lane + 64];
        }
        for (int off = 32; off > 0; off >>= 1) {
            ps += __shfl_down(ps, off);
            pd += __shfl_down(pd, off);
        }
        if (lane == 0) { es[n * 2 + hd] = ps; ed[n * 2 + hd] = pd; }
    }
}

// ---------------- per-dst aggregation with online softmax (wave per node) ----------------
__global__ __launch_bounds__(256) void gat_agg(
    const float* __restrict__ h, const float* __restrict__ es, const float* __restrict__ ed,
    const int* __restrict__ row_ptr, const int* __restrict__ col_src,
    const float* __restrict__ bias, float* __restrict__ out, int n_nodes)
{
    int wave = threadIdx.x >> 6, lane = threadIdx.x & 63;
    int n = blockIdx.x * 4 + wave;
    if (n >= n_nodes) return;
    int e0 = row_ptr[n], e1 = row_ptr[n + 1];
    float edv0 = ed[n * 2 + 0], edv1 = ed[n * 2 + 1];
    float m0 = -INFINITY, m1 = -INFINITY, l0 = 0.f, l1 = 0.f;
    float acc0 = 0.f, acc1 = 0.f, acc2 = 0.f, acc3 = 0.f;
    // channel map: c0=lane(head0), c1=lane+64(head = (lane+64)>=100), c2=lane+128(head1), c3=lane+192(head1, lane<8)
    bool c1h1 = (lane + 64) >= Cch;
    bool c3v  = lane < (HC - 192);
    for (int e = e0; e < e1; e++) {
        int s = col_src[e];
        float s0 = es[s * 2 + 0] + edv0;
        float s1 = es[s * 2 + 1] + edv1;
        s0 = s0 > 0.f ? s0 : SLOPE * s0;
        s1 = s1 > 0.f ? s1 : SLOPE * s1;
        float nm0 = fmaxf(m0, s0), nm1 = fmaxf(m1, s1);
        float sc0 = expf(m0 - nm0), sc1 = expf(m1 - nm1);
        float p0  = expf(s0 - nm0), p1  = expf(s1 - nm1);
        l0 = l0 * sc0 + p0;
        l1 = l1 * sc1 + p1;
        const float* hr = h + (size_t)s * HC;
        float scb = c1h1 ? sc1 : sc0;
        float pb  = c1h1 ? p1 : p0;
        acc0 = acc0 * sc0 + p0 * hr[lane];
        acc1 = acc1 * scb + pb * hr[lane + 64];
        acc2 = acc2 * sc1 + p1 * hr[lane + 128];
        if (c3v) acc3 = acc3 * sc1 + p1 * hr[lane + 192];
        m0 = nm0; m1 = nm1;
    }
    float lb = c1h1 ? l1 : l0;
    size_t base = (size_t)n * HC;
    out[base + lane]        = fmaxf(acc0 / l0 + bias[lane], 0.f);
    out[base + lane + 64]   = fmaxf(acc1 / lb + bias[lane + 64], 0.f);
    out[base + lane + 128]  = fmaxf(acc2 / l1 + bias[lane + 128], 0.f);
    if (c3v) out[base + lane + 192] = fmaxf(acc3 / l1 + bias[lane + 192], 0.f);
}

// ---------------- graph boundaries (batch sorted) ----------------
__global__ void graph_bounds(const int* __restrict__ batch, int* gstart, int n, int g) {
    int i = blockIdx.x * 256 + threadIdx.x;
    if (i >= n) return;
    int b = batch[i];
    int bp = (i == 0) ? -1 : batch[i - 1];
    for (int q = bp + 1; q <= b; q++) gstart[q] = i;
    if (i == n - 1) for (int q = b + 1; q <= g; q++) gstart[q] = n;
}

__global__ __launch_bounds__(256) void pool_mean(
    const float* __restrict__ x, const int* __restrict__ gstart, float* __restrict__ pool)
{
    int g = blockIdx.x;
    int s = gstart[g], e = gstart[g + 1];
    int t = threadIdx.x;
    if (t >= HC) return;
    float sum = 0.f;
    for (int n = s; n < e; n++) sum += x[(size_t)n * HC + t];
    float cnt = (float)(e - s);
    pool[g * HC + t] = sum / fmaxf(cnt, 1.f);
}

// ---------------- small MLP layers (block per row) ----------------
template<int KIN, int KOUT, bool RELU>
__global__ __launch_bounds__(128) void mlp(
    const float* __restrict__ in, const float* __restrict__ W, const float* __restrict__ b,
    float* __restrict__ out)
{
    __shared__ float xi[KIN];
    int g = blockIdx.x;
    for (int k = threadIdx.x; k < KIN; k += blockDim.x) xi[k] = in[g * KIN + k];
    __syncthreads();
    int j = threadIdx.x;
    if (j < KOUT) {
        float s = b[j];
        for (int k = 0; k < KIN; k++) s = fmaf(xi[k], W[k * KOUT + j], s);
        if (RELU) s = fmaxf(s, 0.f);
        out[g * KOUT + j] = s;
    }
}

// ---------------- launch ----------------
extern "C" void kernel_launch(void* const* d_in, const int* in_sizes, int n_in,
                              void* d_out, int out_size, void* d_ws, size_t ws_size,
                              hipStream_t stream) {
    const float* x     = (const float*)d_in[0];
    const int*   ei    = (const int*)d_in[1];
    const int*   batch = (const int*)d_in[2];
    const float *W[5], *asrc[5], *adst[5], *bc[5];
    for (int i = 0; i < 5; i++) {
        W[i]    = (const float*)d_in[3 + i * 4];
        asrc[i] = (const float*)d_in[4 + i * 4];
        adst[i] = (const float*)d_in[5 + i * 4];
        bc[i]   = (const float*)d_in[6 + i * 4];
    }
    const float* lw1 = (const float*)d_in[23];
    const float* lb1 = (const float*)d_in[24];
    const float* lw2 = (const float*)d_in[25];
    const float* lb2 = (const float*)d_in[26];
    const float* lw3 = (const float*)d_in[27];
    const float* lb3 = (const float*)d_in[28];
    float* out = (float*)d_out;

    const int N  = in_sizes[0] / F_IN;
    const int E  = in_sizes[1] / 2;
    const int G  = out_size / 29;
    const int TE = E + N;
    const int* esrc = ei;
    const int* edst = ei + E;

    // workspace carve
    char* p = (char*)d_ws;
    auto carve = [&](size_t bytes) { void* r = (void*)p; p += ((bytes + 255) / 256) * 256; return r; };
    float* bufA    = (float*)carve((size_t)N * HC * 4);   // h
    float* bufB    = (float*)carve((size_t)N * HC * 4);   // layer output
    float* es_     = (float*)carve((size_t)N * 2 * 4);
    float* ed_     = (float*)carve((size_t)N * 2 * 4);
    int*   deg     = (int*)carve((size_t)N * 4);
    int*   incl    = (int*)carve((size_t)N * 4);
    int*   bsums   = (int*)carve(SCAN_BS * 4);
    int*   row_ptr = (int*)carve((size_t)(N + 1) * 4);
    int*   cursor  = (int*)carve((size_t)N * 4);
    int*   col_src = (int*)carve((size_t)TE * 4);
    int*   gstart  = (int*)carve((size_t)(G + 1) * 4);
    float* pool    = (float*)carve((size_t)G * HC * 4);
    float* t1      = (float*)carve((size_t)G * 100 * 4);
    float* t2      = (float*)carve((size_t)G * 100 * 4);

    const int nBlkN   = (N + 255) / 256;
    const int nBlkE   = (E + 255) / 256;
    const int nBlkTE  = (TE + 255) / 256;
    const int nScanB  = (N + SCAN_BS - 1) / SCAN_BS;
    const int nWaveB  = (N + 3) / 4;   // 4 waves/block, wave per node

    // ---- CSR build ----
    init_deg<<<nBlkN, 256, 0, stream>>>(deg, N);
    count_deg<<<nBlkE, 256, 0, stream>>>(edst, deg, E);
    scan_block<<<nScanB, SCAN_BS, 0, stream>>>(deg, incl, bsums, N);
    scan_sums<<<1, SCAN_BS, 0, stream>>>(bsums, nScanB);
    scan_final<<<nScanB, SCAN_BS, 0, stream>>>(incl, deg, bsums, row_ptr, cursor, N);
    fill_csr<<<nBlkTE, 256, 0, stream>>>(esrc, edst, cursor, col_src, E, N);

    // ---- 5 GAT layers ----
    const float* cur = x;
    for (int L = 0; L < 5; L++) {
        int K = (L == 0) ? F_IN : HC;
        dim3 grid((N + BM - 1) / BM, (HC + BN - 1) / BN);
        gemm_f32<<<grid, 256, 0, stream>>>(cur, W[L], bufA, N, K, HC);
        gat_scores<<<nWaveB, 256, 0, stream>>>(bufA, asrc[L], adst[L], es_, ed_, N);
        gat_agg<<<nWaveB, 256, 0, stream>>>(bufA, es_, ed_, row_ptr, col_src, bc[L], bufB, N);
        cur = bufB;
    }

    // ---- pooling ----
    graph_bounds<<<nBlkN, 256, 0, stream>>>(batch, gstart, N, G);
    pool_mean<<<G, 256, 0, stream>>>(bufB, gstart, pool);

    // ---- MLP head ----
    mlp<200, 100, true ><<<G, 128, 0, stream>>>(pool, lw1, lb1, t1);
    mlp<100, 100, true ><<<G, 128, 0, stream>>>(t1, lw2, lb2, t2);
    mlp<100, 29,  false><<<G, 128, 0, stream>>>(t2, lw3, lb3, out);
}

// Round 2
// 1053.981 us; speedup vs baseline: 1.3505x; 1.3505x over previous
//
#include <hip/hip_runtime.h>
#include <hip/hip_bf16.h>
#include <math.h>

// ---------------- constants (from reference) ----------------
#define F_IN   336
#define HC     200      // H*C
#define Cch    100      // channels per head
#define SLOPE  0.2f
#define SCAN_BS 256

// padded dims for MFMA GEMM
#define NPAD   224      // HC padded to 14*16
#define KP0    352      // F_IN padded to mult of 32
#define KP1    224      // HC padded to mult of 32

using short8  = __attribute__((ext_vector_type(8))) short;
using float4v = __attribute__((ext_vector_type(4))) float;

// ---------------- bf16 split helpers ----------------
__device__ inline unsigned short rne_bf16(float v) {
    unsigned int u = __float_as_uint(v);
    return (unsigned short)((u + 0x7fffu + ((u >> 16) & 1u)) >> 16);
}
__device__ inline void split_bf(float v, unsigned short& hi, unsigned short& lo) {
    hi = rne_bf16(v);
    float hv = __uint_as_float(((unsigned int)hi) << 16);
    lo = rne_bf16(v - hv);
}

// ---------------- CSR build ----------------
__global__ void init_deg(int* deg, int n) {
    int i = blockIdx.x * 256 + threadIdx.x;
    if (i < n) deg[i] = 1;   // self-loop
}

__global__ void count_deg(const int* __restrict__ dst, int* deg, int e) {
    int i = blockIdx.x * 256 + threadIdx.x;
    if (i < e) atomicAdd(&deg[dst[i]], 1);
}

__global__ void scan_block(const int* __restrict__ deg, int* incl, int* bsums, int n) {
    __shared__ int sm[SCAN_BS];
    int i = blockIdx.x * SCAN_BS + threadIdx.x;
    int v = (i < n) ? deg[i] : 0;
    sm[threadIdx.x] = v;
    __syncthreads();
    for (int off = 1; off < SCAN_BS; off <<= 1) {
        int t = (threadIdx.x >= off) ? sm[threadIdx.x - off] : 0;
        __syncthreads();
        sm[threadIdx.x] += t;
        __syncthreads();
    }
    if (i < n) incl[i] = sm[threadIdx.x];
    if (threadIdx.x == SCAN_BS - 1) bsums[blockIdx.x] = sm[threadIdx.x];
}

__global__ void scan_sums(int* bsums, int nb) {
    __shared__ int sm[SCAN_BS];
    int v = (threadIdx.x < nb) ? bsums[threadIdx.x] : 0;
    sm[threadIdx.x] = v;
    __syncthreads();
    for (int off = 1; off < SCAN_BS; off <<= 1) {
        int t = (threadIdx.x >= off) ? sm[threadIdx.x - off] : 0;
        __syncthreads();
        sm[threadIdx.x] += t;
        __syncthreads();
    }
    if (threadIdx.x < nb) bsums[threadIdx.x] = sm[threadIdx.x] - v;  // exclusive
}

__global__ void scan_final(const int* __restrict__ incl, const int* __restrict__ deg,
                           const int* __restrict__ bsums, int* row_ptr, int* cursor, int n) {
    int i = blockIdx.x * SCAN_BS + threadIdx.x;
    if (i < n) {
        int inc = incl[i] + bsums[i / SCAN_BS];
        int ex  = inc - deg[i];
        row_ptr[i] = ex;
        cursor[i]  = ex;
        if (i == n - 1) row_ptr[n] = inc;
    }
}

__global__ void fill_csr(const int* __restrict__ src, const int* __restrict__ dst,
                         int* cursor, int* col_src, int e, int n) {
    int i = blockIdx.x * 256 + threadIdx.x;
    int te = e + n;
    if (i >= te) return;
    int s, d;
    if (i < e) { s = src[i]; d = dst[i]; }
    else       { s = i - e;  d = i - e; }
    int pos = atomicAdd(&cursor[d], 1);
    col_src[pos] = s;
}

// ---------------- split conversions ----------------
// x [N,336] fp32 -> Ah/Al [N,352] bf16 (zero pad)
__global__ void conv_x(const float* __restrict__ x, unsigned short* __restrict__ Ah,
                       unsigned short* __restrict__ Al, int n_nodes) {
    int i = blockIdx.x * 256 + threadIdx.x;
    int tot = n_nodes * KP0;
    if (i >= tot) return;
    int row = i / KP0, col = i - row * KP0;
    float v = (col < F_IN) ? x[(size_t)row * F_IN + col] : 0.f;
    unsigned short hi, lo;
    split_bf(v, hi, lo);
    Ah[i] = hi; Al[i] = lo;
}

// W [K,200] fp32 -> Wth/Wtl [224,Kp] bf16 transposed (zero pad)
__global__ void conv_w(const float* __restrict__ W, unsigned short* __restrict__ Bh,
                       unsigned short* __restrict__ Bl, int K, int Kp) {
    int i = blockIdx.x * 256 + threadIdx.x;
    int tot = NPAD * Kp;
    if (i >= tot) return;
    int n = i / Kp, k = i - n * Kp;
    float v = (n < HC && k < K) ? W[(size_t)k * HC + n] : 0.f;
    unsigned short hi, lo;
    split_bf(v, hi, lo);
    Bh[i] = hi; Bl[i] = lo;
}

// ---------------- split-bf16 MFMA GEMM: h[M,200] = A[M,Kp] @ Wt^T ----------------
// block tile 64(M) x 224(N), BK=32, 4 waves in 2x2, wave tile 32x112 (2x7 mfma tiles)
#define LDK 40   // LDS k-stride (32 + 8 pad -> 2-way bank conflicts only)
__global__ __launch_bounds__(256, 2) void gemm_split(
    const unsigned short* __restrict__ Ah, const unsigned short* __restrict__ Al,
    const unsigned short* __restrict__ Bh, const unsigned short* __restrict__ Bl,
    float* __restrict__ h, int M, int Kp)
{
    __shared__ unsigned short As[2][64][LDK];
    __shared__ unsigned short Bs[2][NPAD][LDK];
    int tid  = threadIdx.x;
    int wave = tid >> 6, lane = tid & 63;
    int quad = lane >> 4, l16 = lane & 15;
    int wm = (wave >> 1) * 32;
    int wn = (wave & 1) * 112;
    int r0 = blockIdx.x * 64;

    float4v acc[2][7];
#pragma unroll
    for (int mt = 0; mt < 2; mt++)
#pragma unroll
        for (int nt = 0; nt < 7; nt++)
            acc[mt][nt] = (float4v){0.f, 0.f, 0.f, 0.f};

    for (int k0 = 0; k0 < Kp; k0 += 32) {
        // stage A: 2 splits * 64 rows * 4 chunks(16B) = 512 chunks / 256 thr
#pragma unroll
        for (int i = 0; i < 2; i++) {
            int c = tid + 256 * i;
            int s = c >> 8;
            int cc = c & 255;
            int row = cc >> 2, kc = (cc & 3) * 8;
            const unsigned short* g = s ? Al : Ah;
            uint4 v = make_uint4(0u, 0u, 0u, 0u);
            int gr = r0 + row;
            if (gr < M) v = *(const uint4*)(g + (size_t)gr * Kp + k0 + kc);
            *(uint4*)&As[s][row][kc] = v;
        }
        // stage B: 2 splits * 224 rows * 4 chunks = 1792 chunks / 256 thr
#pragma unroll
        for (int i = 0; i < 7; i++) {
            int c = tid + 256 * i;
            int s = (c >= 896) ? 1 : 0;
            int cc = c - s * 896;
            int row = cc >> 2, kc = (cc & 3) * 8;
            const unsigned short* g = s ? Bl : Bh;
            *(uint4*)&Bs[s][row][kc] = *(const uint4*)(g + (size_t)row * Kp + k0 + kc);
        }
        __syncthreads();

        short8 a_h[2], a_l[2];
#pragma unroll
        for (int mt = 0; mt < 2; mt++) {
            a_h[mt] = *(const short8*)&As[0][wm + mt * 16 + l16][quad * 8];
            a_l[mt] = *(const short8*)&As[1][wm + mt * 16 + l16][quad * 8];
        }
#pragma unroll
        for (int nt = 0; nt < 7; nt++) {
            short8 b_h = *(const short8*)&Bs[0][wn + nt * 16 + l16][quad * 8];
            short8 b_l = *(const short8*)&Bs[1][wn + nt * 16 + l16][quad * 8];
#pragma unroll
            for (int mt = 0; mt < 2; mt++) {
                acc[mt][nt] = __builtin_amdgcn_mfma_f32_16x16x32_bf16(a_h[mt], b_h, acc[mt][nt], 0, 0, 0);
                acc[mt][nt] = __builtin_amdgcn_mfma_f32_16x16x32_bf16(a_h[mt], b_l, acc[mt][nt], 0, 0, 0);
                acc[mt][nt] = __builtin_amdgcn_mfma_f32_16x16x32_bf16(a_l[mt], b_h, acc[mt][nt], 0, 0, 0);
            }
        }
        __syncthreads();
    }

    // epilogue: D row = quad*4+reg, col = l16 (verified m89 layout)
#pragma unroll
    for (int mt = 0; mt < 2; mt++) {
#pragma unroll
        for (int nt = 0; nt < 7; nt++) {
            int col = wn + nt * 16 + l16;
            if (col >= HC) continue;
#pragma unroll
            for (int r = 0; r < 4; r++) {
                int grow = r0 + wm + mt * 16 + quad * 4 + r;
                if (grow < M) h[(size_t)grow * HC + col] = acc[mt][nt][r];
            }
        }
    }
}

// ---------------- attention scores es/ed (wave per node) ----------------
__global__ __launch_bounds__(256) void gat_scores(
    const float* __restrict__ h, const float* __restrict__ asrc, const float* __restrict__ adst,
    float* __restrict__ es, float* __restrict__ ed, int n_nodes)
{
    int wave = threadIdx.x >> 6, lane = threadIdx.x & 63;
    int n = blockIdx.x * 4 + wave;
    if (n >= n_nodes) return;
#pragma unroll
    for (int hd = 0; hd < 2; hd++) {
        const float* hr = h + (size_t)n * HC + hd * Cch;
        const float* as = asrc + hd * Cch;
        const float* ad = adst + hd * Cch;
        float v = hr[lane];
        float ps = v * as[lane];
        float pd = v * ad[lane];
        if (lane < Cch - 64) {
            float v2 = hr[lane + 64];
            ps += v2 * as[lane + 64];
            pd += v2 * ad[lane + 64];
        }
        for (int off = 32; off > 0; off >>= 1) {
            ps += __shfl_down(ps, off);
            pd += __shfl_down(pd, off);
        }
        if (lane == 0) { es[n * 2 + hd] = ps; ed[n * 2 + hd] = pd; }
    }
}

// ---------------- per-dst aggregation, online softmax (wave per node) ----------------
// WF: write fp32 out (stride 200). WB: write bf16 hi/lo split (stride 224, zero-padded).
template<bool WF, bool WB>
__global__ __launch_bounds__(256) void gat_agg(
    const float* __restrict__ h, const float* __restrict__ es, const float* __restrict__ ed,
    const int* __restrict__ row_ptr, const int* __restrict__ col_src,
    const float* __restrict__ bias, float* __restrict__ outF,
    unsigned short* __restrict__ oh, unsigned short* __restrict__ ol, int n_nodes)
{
    int wave = threadIdx.x >> 6, lane = threadIdx.x & 63;
    int n = blockIdx.x * 4 + wave;
    if (n >= n_nodes) return;
    int e0 = row_ptr[n], e1 = row_ptr[n + 1];
    float edv0 = ed[n * 2 + 0], edv1 = ed[n * 2 + 1];
    float m0 = -INFINITY, m1 = -INFINITY, l0 = 0.f, l1 = 0.f;
    float acc0 = 0.f, acc1 = 0.f, acc2 = 0.f, acc3 = 0.f;
    bool c1h1 = (lane + 64) >= Cch;   // channel lane+64 belongs to head1?
    bool c3v  = lane < (HC - 192);
    for (int e = e0; e < e1; e++) {
        int s = col_src[e];
        float s0 = es[s * 2 + 0] + edv0;
        float s1 = es[s * 2 + 1] + edv1;
        s0 = s0 > 0.f ? s0 : SLOPE * s0;
        s1 = s1 > 0.f ? s1 : SLOPE * s1;
        float nm0 = fmaxf(m0, s0), nm1 = fmaxf(m1, s1);
        float sc0 = expf(m0 - nm0), sc1 = expf(m1 - nm1);
        float p0  = expf(s0 - nm0), p1  = expf(s1 - nm1);
        l0 = l0 * sc0 + p0;
        l1 = l1 * sc1 + p1;
        const float* hr = h + (size_t)s * HC;
        float scb = c1h1 ? sc1 : sc0;
        float pb  = c1h1 ? p1 : p0;
        acc0 = acc0 * sc0 + p0 * hr[lane];
        acc1 = acc1 * scb + pb * hr[lane + 64];
        acc2 = acc2 * sc1 + p1 * hr[lane + 128];
        if (c3v) acc3 = acc3 * sc1 + p1 * hr[lane + 192];
        m0 = nm0; m1 = nm1;
    }
    float lb = c1h1 ? l1 : l0;
    float r0v = fmaxf(acc0 / l0 + bias[lane], 0.f);
    float r1v = fmaxf(acc1 / lb + bias[lane + 64], 0.f);
    float r2v = fmaxf(acc2 / l1 + bias[lane + 128], 0.f);
    float r3v = c3v ? fmaxf(acc3 / l1 + bias[lane + 192], 0.f) : 0.f;
    if (WF) {
        size_t base = (size_t)n * HC;
        outF[base + lane]       = r0v;
        outF[base + lane + 64]  = r1v;
        outF[base + lane + 128] = r2v;
        if (c3v) outF[base + lane + 192] = r3v;
    }
    if (WB) {
        size_t b = (size_t)n * NPAD;
        unsigned short hi, lo;
        split_bf(r0v, hi, lo); oh[b + lane] = hi;       ol[b + lane] = lo;
        split_bf(r1v, hi, lo); oh[b + lane + 64] = hi;  ol[b + lane + 64] = lo;
        split_bf(r2v, hi, lo); oh[b + lane + 128] = hi; ol[b + lane + 128] = lo;
        if (c3v) {
            split_bf(r3v, hi, lo); oh[b + lane + 192] = hi; ol[b + lane + 192] = lo;
        } else if (lane < 32) {           // zero the pad cols 200..223
            oh[b + lane + 192] = 0; ol[b + lane + 192] = 0;
        }
    }
}

// ---------------- graph boundaries (batch sorted) ----------------
__global__ void graph_bounds(const int* __restrict__ batch, int* gstart, int n, int g) {
    int i = blockIdx.x * 256 + threadIdx.x;
    if (i >= n) return;
    int b = batch[i];
    int bp = (i == 0) ? -1 : batch[i - 1];
    for (int q = bp + 1; q <= b; q++) gstart[q] = i;
    if (i == n - 1) for (int q = b + 1; q <= g; q++) gstart[q] = n;
}

__global__ __launch_bounds__(256) void pool_mean(
    const float* __restrict__ x, const int* __restrict__ gstart, float* __restrict__ pool)
{
    int g = blockIdx.x;
    int s = gstart[g], e = gstart[g + 1];
    int t = threadIdx.x;
    if (t >= HC) return;
    float sum = 0.f;
    for (int n = s; n < e; n++) sum += x[(size_t)n * HC + t];
    float cnt = (float)(e - s);
    pool[g * HC + t] = sum / fmaxf(cnt, 1.f);
}

// ---------------- small MLP layers (block per row) ----------------
template<int KIN, int KOUT, bool RELU>
__global__ __launch_bounds__(128) void mlp(
    const float* __restrict__ in, const float* __restrict__ W, const float* __restrict__ b,
    float* __restrict__ out)
{
    __shared__ float xi[KIN];
    int g = blockIdx.x;
    for (int k = threadIdx.x; k < KIN; k += blockDim.x) xi[k] = in[g * KIN + k];
    __syncthreads();
    int j = threadIdx.x;
    if (j < KOUT) {
        float s = b[j];
        for (int k = 0; k < KIN; k++) s = fmaf(xi[k], W[k * KOUT + j], s);
        if (RELU) s = fmaxf(s, 0.f);
        out[g * KOUT + j] = s;
    }
}

// ---------------- launch ----------------
extern "C" void kernel_launch(void* const* d_in, const int* in_sizes, int n_in,
                              void* d_out, int out_size, void* d_ws, size_t ws_size,
                              hipStream_t stream) {
    const float* x     = (const float*)d_in[0];
    const int*   ei    = (const int*)d_in[1];
    const int*   batch = (const int*)d_in[2];
    const float *W[5], *asrc[5], *adst[5], *bc[5];
    for (int i = 0; i < 5; i++) {
        W[i]    = (const float*)d_in[3 + i * 4];
        asrc[i] = (const float*)d_in[4 + i * 4];
        adst[i] = (const float*)d_in[5 + i * 4];
        bc[i]   = (const float*)d_in[6 + i * 4];
    }
    const float* lw1 = (const float*)d_in[23];
    const float* lb1 = (const float*)d_in[24];
    const float* lw2 = (const float*)d_in[25];
    const float* lb2 = (const float*)d_in[26];
    const float* lw3 = (const float*)d_in[27];
    const float* lb3 = (const float*)d_in[28];
    float* out = (float*)d_out;

    const int N  = in_sizes[0] / F_IN;
    const int E  = in_sizes[1] / 2;
    const int G  = out_size / 29;
    const int TE = E + N;
    const int* esrc = ei;
    const int* edst = ei + E;

    // workspace carve
    char* p = (char*)d_ws;
    auto carve = [&](size_t bytes) { void* r = (void*)p; p += ((bytes + 255) / 256) * 256; return r; };
    float*          hbuf = (float*)carve((size_t)N * HC * 4);          // GEMM out h (fp32)
    unsigned short* Ah   = (unsigned short*)carve((size_t)N * KP0 * 2);
    unsigned short* Al   = (unsigned short*)carve((size_t)N * KP0 * 2);
    float*          outF = (float*)Ah;  // aliases Ah/Al (dead by the time L5 agg writes)
    unsigned short* Wth  = (unsigned short*)carve((size_t)NPAD * KP0 * 2);
    unsigned short* Wtl  = (unsigned short*)carve((size_t)NPAD * KP0 * 2);
    float* es_     = (float*)carve((size_t)N * 2 * 4);
    float* ed_     = (float*)carve((size_t)N * 2 * 4);
    int*   deg     = (int*)carve((size_t)N * 4);
    int*   incl    = (int*)carve((size_t)N * 4);
    int*   bsums   = (int*)carve(SCAN_BS * 4);
    int*   row_ptr = (int*)carve((size_t)(N + 1) * 4);
    int*   cursor  = (int*)carve((size_t)N * 4);
    int*   col_src = (int*)carve((size_t)TE * 4);
    int*   gstart  = (int*)carve((size_t)(G + 1) * 4);
    float* pool    = (float*)carve((size_t)G * HC * 4);
    float* t1      = (float*)carve((size_t)G * 100 * 4);
    float* t2      = (float*)carve((size_t)G * 100 * 4);

    const int nBlkN   = (N + 255) / 256;
    const int nBlkE   = (E + 255) / 256;
    const int nBlkTE  = (TE + 255) / 256;
    const int nScanB  = (N + SCAN_BS - 1) / SCAN_BS;
    const int nWaveB  = (N + 3) / 4;
    const int nGemmB  = (N + 63) / 64;

    // ---- CSR build ----
    init_deg<<<nBlkN, 256, 0, stream>>>(deg, N);
    count_deg<<<nBlkE, 256, 0, stream>>>(edst, deg, E);
    scan_block<<<nScanB, SCAN_BS, 0, stream>>>(deg, incl, bsums, N);
    scan_sums<<<1, SCAN_BS, 0, stream>>>(bsums, nScanB);
    scan_final<<<nScanB, SCAN_BS, 0, stream>>>(incl, deg, bsums, row_ptr, cursor, N);
    fill_csr<<<nBlkTE, 256, 0, stream>>>(esrc, edst, cursor, col_src, E, N);

    // ---- input split ----
    conv_x<<<(N * KP0 + 255) / 256, 256, 0, stream>>>(x, Ah, Al, N);

    // ---- 5 GAT layers ----
    for (int L = 0; L < 5; L++) {
        int K  = (L == 0) ? F_IN : HC;
        int Kp = (L == 0) ? KP0 : KP1;
        conv_w<<<(NPAD * Kp + 255) / 256, 256, 0, stream>>>(W[L], Wth, Wtl, K, Kp);
        gemm_split<<<nGemmB, 256, 0, stream>>>(Ah, Al, Wth, Wtl, hbuf, N, Kp);
        gat_scores<<<nWaveB, 256, 0, stream>>>(hbuf, asrc[L], adst[L], es_, ed_, N);
        if (L < 4)
            gat_agg<false, true><<<nWaveB, 256, 0, stream>>>(hbuf, es_, ed_, row_ptr, col_src,
                                                             bc[L], nullptr, Ah, Al, N);
        else
            gat_agg<true, false><<<nWaveB, 256, 0, stream>>>(hbuf, es_, ed_, row_ptr, col_src,
                                                             bc[L], outF, nullptr, nullptr, N);
    }

    // ---- pooling ----
    graph_bounds<<<nBlkN, 256, 0, stream>>>(batch, gstart, N, G);
    pool_mean<<<G, 256, 0, stream>>>(outF, gstart, pool);

    // ---- MLP head ----
    mlp<200, 100, true ><<<G, 128, 0, stream>>>(pool, lw1, lb1, t1);
    mlp<100, 100, true ><<<G, 128, 0, stream>>>(t1, lw2, lb2, t2);
    mlp<100, 29,  false><<<G, 128, 0, stream>>>(t2, lw3, lb3, out);
}